// Round 4
// baseline (1508.082 us; speedup 1.0000x reference)
//
#include <hip/hip_runtime.h>
#include <math.h>

// GNNLayer: 4-head GAT-like layer.
//   feats[h] = relu(x @ W1[h] + b1[h]) @ W2[h] + b2[h]            [N,64]
//   score[e] = dot(f_src, aw[0:64]) + dot(f_dst, aw[64:128]) + aw[128]*elem + ab
//   w = exp(score - global_max_per_head)
//   out[n, h*64+d] = sum_{e: src=n} w*f_dst[d] / sum w
//
// Strategy:
//   - fused 2-layer MLP kernel also emits s1[n]=feats[n].aw1, s2[n]=feats[n].aw2
//     so edge score = s1[src]+s2[dst]+c*elem+b (no per-edge feature gather for scores)
//   - CSR by src (count/scan/scatter) then pull-aggregation: 1 wave per (node,head),
//     lane = output dim. No atomics on the output.

#define N_HEADS 4
#define IN_DIM 256
#define HID_DIM 256
#define OUT_DIM 64
#define ATT_STRIDE (2 * OUT_DIM + 1) // 129
#define TM 32

// ---------------- CSR construction ----------------

__global__ __launch_bounds__(256) void count_kernel(const int* __restrict__ src,
                                                    int* __restrict__ cnt, int E) {
  int e = blockIdx.x * 256 + threadIdx.x;
  if (e < E) atomicAdd(&cnt[src[e]], 1);
}

__global__ __launch_bounds__(1024) void scan_kernel(const int* __restrict__ cnt,
                                                    int* __restrict__ offs, int N) {
  __shared__ int part[1024];
  int t = threadIdx.x;
  int chunk = (N + 1023) >> 10;
  int s0 = t * chunk;
  int s1e = min(s0 + chunk, N);
  int sum = 0;
  for (int i = s0; i < s1e; ++i) sum += cnt[i];
  part[t] = sum;
  __syncthreads();
  // Hillis-Steele inclusive scan over 1024 partials
  for (int off = 1; off < 1024; off <<= 1) {
    int v = (t >= off) ? part[t - off] : 0;
    __syncthreads();
    part[t] += v;
    __syncthreads();
  }
  int run = (t == 0) ? 0 : part[t - 1];
  for (int i = s0; i < s1e; ++i) { offs[i] = run; run += cnt[i]; }
  if (t == 0) offs[N] = part[1023];
}

__global__ __launch_bounds__(256) void scatter_kernel(const int* __restrict__ src,
                                                      const int* __restrict__ offs,
                                                      int* __restrict__ cur,
                                                      int* __restrict__ eid, int E) {
  int e = blockIdx.x * 256 + threadIdx.x;
  if (e < E) {
    int s = src[e];
    int pos = offs[s] + atomicAdd(&cur[s], 1);
    eid[pos] = e;
  }
}

// ---------------- fused per-head MLP + attention projections ----------------
// grid: (ceil(N/TM), N_HEADS), block: 256 threads.
// Thread j owns hidden column j for TM nodes. Then the block transposes the
// hidden tile through LDS and computes the 64-dim output per node, plus the
// two attention dot products via wave shuffle-reduction.

__global__ __launch_bounds__(256) void feats_kernel(
    const float* __restrict__ x, const float* __restrict__ W1,
    const float* __restrict__ b1, const float* __restrict__ W2,
    const float* __restrict__ b2, const float* __restrict__ attn_w,
    const float* __restrict__ attn_b, float* __restrict__ feats,
    float* __restrict__ s1, float* __restrict__ s2, int N) {
  __shared__ float xs[TM * 32];    // x tile [m][k], 4 KB
  __shared__ float wsb[32 * 256];  // W1 tile [k][j], 32 KB; reused as hid [m][j]

  int h = blockIdx.y;
  int n0 = blockIdx.x * TM;
  int tid = threadIdx.x;
  const float* W1h = W1 + (size_t)h * IN_DIM * HID_DIM;

  float acc[TM];
  float bj = b1[h * HID_DIM + tid];
#pragma unroll
  for (int m = 0; m < TM; ++m) acc[m] = bj;

  for (int kt = 0; kt < IN_DIM / 32; ++kt) {
    // load x tile: 1024 floats = 256 float4, one per thread
    {
      int m = tid >> 3, k4 = (tid & 7) << 2;
      int n = n0 + m;
      float4 v = make_float4(0.f, 0.f, 0.f, 0.f);
      if (n < N) v = *(const float4*)(x + (size_t)n * IN_DIM + kt * 32 + k4);
      *(float4*)(xs + m * 32 + k4) = v;
    }
    // load W1 tile: 8192 floats = 2048 float4, 8 per thread
#pragma unroll
    for (int i = 0; i < 8; ++i) {
      int flat4 = i * 256 + tid;
      int k = flat4 >> 6, j4 = (flat4 & 63) << 2;
      *(float4*)(wsb + k * 256 + j4) =
          *(const float4*)(W1h + (size_t)(kt * 32 + k) * HID_DIM + j4);
    }
    __syncthreads();
    for (int k = 0; k < 32; ++k) {
      float w = wsb[k * 256 + tid];
#pragma unroll
      for (int m = 0; m < TM; ++m) acc[m] = fmaf(xs[m * 32 + k], w, acc[m]);
    }
    __syncthreads();
  }

  // relu + transpose hidden through LDS (reuse wsb as hid[m][j])
#pragma unroll
  for (int m = 0; m < TM; ++m) wsb[m * 256 + tid] = fmaxf(acc[m], 0.0f);
  __syncthreads();

  // second layer: wave mg handles nodes m = i*4+mg, lane d = output dim
  int d = tid & 63, mg = tid >> 6;
  const float* W2h = W2 + (size_t)h * HID_DIM * OUT_DIM;
  float acc2[8];
  float b2d = b2[h * OUT_DIM + d];
#pragma unroll
  for (int i = 0; i < 8; ++i) acc2[i] = b2d;
  for (int j = 0; j < HID_DIM; ++j) {
    float w2 = W2h[j * OUT_DIM + d];
#pragma unroll
    for (int i = 0; i < 8; ++i) {
      int m = i * 4 + mg;
      acc2[i] = fmaf(wsb[m * 256 + j], w2, acc2[i]);
    }
  }

  const float* awh = attn_w + h * ATT_STRIDE;
  float a1 = awh[d], a2 = awh[OUT_DIM + d];
#pragma unroll
  for (int i = 0; i < 8; ++i) {
    int m = i * 4 + mg;
    int n = n0 + m;
    float p1 = acc2[i] * a1;
    float p2 = acc2[i] * a2;
#pragma unroll
    for (int off = 32; off > 0; off >>= 1) {
      p1 += __shfl_down(p1, off, 64);
      p2 += __shfl_down(p2, off, 64);
    }
    if (n < N) {
      feats[((size_t)h * N + n) * OUT_DIM + d] = acc2[i];
      if (d == 0) {
        s1[(size_t)h * N + n] = p1;
        s2[(size_t)h * N + n] = p2;
      }
    }
  }
}

// ---------------- global per-head max of edge scores ----------------

__global__ __launch_bounds__(256) void edgemax_kernel(
    const int* __restrict__ src, const int* __restrict__ dst,
    const float* __restrict__ elem, const float* __restrict__ s1,
    const float* __restrict__ s2, const float* __restrict__ attn_w,
    const float* __restrict__ attn_b, float* __restrict__ blockmax, int N, int E) {
  int e = blockIdx.x * 256 + threadIdx.x;
  float sc[N_HEADS];
  if (e < E) {
    int s = src[e], dn = dst[e];
    float el = elem[e];
#pragma unroll
    for (int h = 0; h < N_HEADS; ++h)
      sc[h] = s1[(size_t)h * N + s] + s2[(size_t)h * N + dn] +
              attn_w[h * ATT_STRIDE + 2 * OUT_DIM] * el + attn_b[h];
  } else {
#pragma unroll
    for (int h = 0; h < N_HEADS; ++h) sc[h] = -INFINITY;
  }
  __shared__ float wm[N_HEADS][4];
  int lane = threadIdx.x & 63, wv = threadIdx.x >> 6;
#pragma unroll
  for (int h = 0; h < N_HEADS; ++h) {
    float m = sc[h];
#pragma unroll
    for (int off = 32; off > 0; off >>= 1) m = fmaxf(m, __shfl_down(m, off, 64));
    if (lane == 0) wm[h][wv] = m;
  }
  __syncthreads();
  if (threadIdx.x < N_HEADS) {
    int h = threadIdx.x;
    float m = fmaxf(fmaxf(wm[h][0], wm[h][1]), fmaxf(wm[h][2], wm[h][3]));
    blockmax[blockIdx.x * N_HEADS + h] = m;
  }
}

__global__ __launch_bounds__(256) void reducemax_kernel(
    const float* __restrict__ blockmax, float* __restrict__ maxs, int nb) {
  __shared__ float red[256];
  int tid = threadIdx.x;
  for (int h = 0; h < N_HEADS; ++h) {
    float m = -INFINITY;
    for (int i = tid; i < nb; i += 256) m = fmaxf(m, blockmax[i * N_HEADS + h]);
    red[tid] = m;
    __syncthreads();
    for (int s = 128; s > 0; s >>= 1) {
      if (tid < s) red[tid] = fmaxf(red[tid], red[tid + s]);
      __syncthreads();
    }
    if (tid == 0) maxs[h] = red[0];
    __syncthreads();
  }
}

// ---------------- pull aggregation ----------------
// block = 4 waves = 4 heads for node blockIdx.x; lane = output dim.

__global__ __launch_bounds__(256) void aggregate_kernel(
    const int* __restrict__ dst, const float* __restrict__ elem,
    const int* __restrict__ offs, const int* __restrict__ eid,
    const float* __restrict__ s1, const float* __restrict__ s2,
    const float* __restrict__ feats, const float* __restrict__ attn_w,
    const float* __restrict__ attn_b, const float* __restrict__ maxs,
    float* __restrict__ out, int N) {
  int n = blockIdx.x;
  int h = threadIdx.x >> 6, d = threadIdx.x & 63;
  int beg = offs[n], end = offs[n + 1];
  float s1n = s1[(size_t)h * N + n];
  float awe = attn_w[h * ATT_STRIDE + 2 * OUT_DIM];
  float ab = attn_b[h];
  float mx = maxs[h];
  const float* fh = feats + (size_t)h * N * OUT_DIM;
  const float* s2h = s2 + (size_t)h * N;
  float acc = 0.f, rs = 0.f;
  for (int p = beg; p < end; ++p) {
    int e = eid[p];
    int dn = dst[e];
    float w = __expf(s1n + s2h[dn] + awe * elem[e] + ab - mx);
    acc = fmaf(w, fh[(size_t)dn * OUT_DIM + d], acc);
    rs += w;
  }
  out[(size_t)n * (N_HEADS * OUT_DIM) + h * OUT_DIM + d] = acc / rs;
}

// ---------------- launch ----------------

extern "C" void kernel_launch(void* const* d_in, const int* in_sizes, int n_in,
                              void* d_out, int out_size, void* d_ws, size_t ws_size,
                              hipStream_t stream) {
  const float* x = (const float*)d_in[0];
  const int* idx = (const int*)d_in[1];
  const float* elem = (const float*)d_in[2];
  const float* W1 = (const float*)d_in[3];
  const float* b1 = (const float*)d_in[4];
  const float* W2 = (const float*)d_in[5];
  const float* b2 = (const float*)d_in[6];
  const float* attn_w = (const float*)d_in[7];
  const float* attn_b = (const float*)d_in[8];
  float* out = (float*)d_out;

  int N = in_sizes[0] / IN_DIM; // 50000
  int E = in_sizes[2];          // 800000
  const int* src = idx;
  const int* dst = idx + E;
  int nb = (E + 255) / 256;

  // workspace layout (~57 MB)
  float* feats = (float*)d_ws;                             // H*N*64
  float* s1 = feats + (size_t)N_HEADS * N * OUT_DIM;       // H*N
  float* s2 = s1 + (size_t)N_HEADS * N;                    // H*N
  float* blockmax = s2 + (size_t)N_HEADS * N;              // nb*H
  float* maxs = blockmax + (size_t)nb * N_HEADS;           // 4 (padded 64)
  int* offs = (int*)(maxs + 64);                           // N+1 (padded)
  int* cur = offs + (N + 64);                              // N
  int* eid = cur + (N + 64);                               // E

  hipMemsetAsync(cur, 0, sizeof(int) * (size_t)N, stream);
  count_kernel<<<nb, 256, 0, stream>>>(src, cur, E);
  scan_kernel<<<1, 1024, 0, stream>>>(cur, offs, N);
  hipMemsetAsync(cur, 0, sizeof(int) * (size_t)N, stream);
  scatter_kernel<<<nb, 256, 0, stream>>>(src, offs, cur, eid, E);

  dim3 g((N + TM - 1) / TM, N_HEADS);
  feats_kernel<<<g, 256, 0, stream>>>(x, W1, b1, W2, b2, attn_w, attn_b, feats,
                                      s1, s2, N);
  edgemax_kernel<<<nb, 256, 0, stream>>>(src, dst, elem, s1, s2, attn_w, attn_b,
                                         blockmax, N, E);
  reducemax_kernel<<<1, 256, 0, stream>>>(blockmax, maxs, nb);
  aggregate_kernel<<<N, 256, 0, stream>>>(dst, elem, offs, eid, s1, s2, feats,
                                          attn_w, attn_b, maxs, out, N);
}

// Round 7
// 711.606 us; speedup vs baseline: 2.1193x; 2.1193x over previous
//
#include <hip/hip_runtime.h>
#include <math.h>

// GNNLayer: 4-head GAT-like layer, MFMA edition.
//   feats[h] = relu(x @ W1[h] + b1[h]) @ W2[h] + b2[h]            [N,64]
//   score[e] = s1[src]+s2[dst]+aw_e*elem+ab ; w = exp(score - head_max)
//   out[n, h*64+d] = sum w*f_dst / sum w      (CSR-by-src pull, no atomics)
//
// Round 4->5 change: feats_kernel rewritten on v_mfma_f32_16x16x32_bf16
// (fp32 accumulate). Baseline feats was LDS-issue-bound fp32 vector FMA
// (1054us, MfmaUtil=0, VALUBusy=61%). Weights pre-transposed+bf16-converted
// so B fragments are 16B/lane contiguous reads from L2-hot memory.

#define N_HEADS 4
#define IN_DIM 256
#define HID_DIM 256
#define OUT_DIM 64
#define ATT_STRIDE (2 * OUT_DIM + 1) // 129
#define LDSP 264                     // padded bf16 row stride (528 B): breaks bank alignment

typedef __attribute__((ext_vector_type(8))) short bf16x8;
typedef __attribute__((ext_vector_type(4))) float f32x4;

__device__ __forceinline__ unsigned short bf16rne(float f) {
  unsigned int u = __float_as_uint(f);
  u += 0x7fffu + ((u >> 16) & 1u);
  return (unsigned short)(u >> 16);
}

// ---------------- weight convert: W1T[h][j][k], W2T[h][d][k] in bf16 ----------------

#define W1N (N_HEADS * IN_DIM * HID_DIM)
#define W2N (N_HEADS * HID_DIM * OUT_DIM)

__global__ __launch_bounds__(256) void convw_kernel(const float* __restrict__ W1,
                                                    const float* __restrict__ W2,
                                                    unsigned short* __restrict__ W1T,
                                                    unsigned short* __restrict__ W2T) {
  int id = blockIdx.x * 256 + threadIdx.x;
  if (id < W1N) {
    int k = id & 255, j = (id >> 8) & 255, h = id >> 16;
    W1T[id] = bf16rne(W1[((size_t)h * 256 + k) * 256 + j]);
  } else if (id < W1N + W2N) {
    int t = id - W1N;
    int k = t & 255, d = (t >> 8) & 63, h = t >> 14;
    W2T[t] = bf16rne(W2[((size_t)h * 256 + k) * 64 + d]);
  }
}

// ---------------- CSR construction ----------------

__global__ __launch_bounds__(256) void count_kernel(const int* __restrict__ src,
                                                    int* __restrict__ cnt, int E) {
  int e = blockIdx.x * 256 + threadIdx.x;
  if (e < E) atomicAdd(&cnt[src[e]], 1);
}

__global__ __launch_bounds__(1024) void scan_kernel(const int* __restrict__ cnt,
                                                    int* __restrict__ offs, int N) {
  __shared__ int part[1024];
  int t = threadIdx.x;
  int chunk = (N + 1023) >> 10;
  int s0 = t * chunk;
  int s1e = min(s0 + chunk, N);
  int sum = 0;
  for (int i = s0; i < s1e; ++i) sum += cnt[i];
  part[t] = sum;
  __syncthreads();
  for (int off = 1; off < 1024; off <<= 1) {
    int v = (t >= off) ? part[t - off] : 0;
    __syncthreads();
    part[t] += v;
    __syncthreads();
  }
  int run = (t == 0) ? 0 : part[t - 1];
  for (int i = s0; i < s1e; ++i) { offs[i] = run; run += cnt[i]; }
  if (t == 0) offs[N] = part[1023];
}

__global__ __launch_bounds__(256) void scatter_kernel(const int* __restrict__ src,
                                                      const int* __restrict__ offs,
                                                      int* __restrict__ cur,
                                                      int* __restrict__ eid, int E) {
  int e = blockIdx.x * 256 + threadIdx.x;
  if (e < E) {
    int s = src[e];
    int pos = offs[s] + atomicAdd(&cur[s], 1);
    eid[pos] = e;
  }
}

// ---------------- fused MFMA MLP + attention projections ----------------
// grid: (ceil(N/64), N_HEADS), block 256 = 4 waves.
// Layer1: 64x256 = x_tile(64x256) @ W1h; wave w owns 64-col strip (4x4 frags).
// Layer2: 64x64 = hid(64x256) @ W2h; wave w owns 16-row strip (1x4 frags).
// Fragment maps (verified m89/m92): A/B lane&15=m/n, k=8*(lane>>4)+j;
//                                   D col=lane&15, row=4*(lane>>4)+reg.

__global__ __launch_bounds__(256) void feats_kernel(
    const float* __restrict__ x, const unsigned short* __restrict__ W1T,
    const float* __restrict__ b1, const unsigned short* __restrict__ W2T,
    const float* __restrict__ b2, const float* __restrict__ attn_w,
    const float* __restrict__ attn_b, float* __restrict__ feats,
    float* __restrict__ s1, float* __restrict__ s2, int N) {
  __shared__ __align__(16) unsigned short xs[64 * LDSP]; // 33.8 KB
  __shared__ __align__(16) unsigned short hs[64 * LDSP]; // 33.8 KB

  int h = blockIdx.y;
  int n0 = blockIdx.x * 64;
  int tid = threadIdx.x;
  int w = tid >> 6, l = tid & 63;
  int lr = l & 15, kb = l >> 4;

  // ---- stage x tile (f32 -> bf16 LDS), zero-fill rows >= N ----
#pragma unroll
  for (int i = 0; i < 8; ++i) {
    int flat = i * 2048 + tid * 8; // 8 f32 per thread per iter
    int r = flat >> 8, c = flat & 255;
    int n = n0 + r;
    float4 v0 = make_float4(0.f, 0.f, 0.f, 0.f), v1 = v0;
    if (n < N) {
      const float* p = x + (size_t)n * IN_DIM + c;
      v0 = *(const float4*)p;
      v1 = *(const float4*)(p + 4);
    }
    uint4 pk;
    pk.x = (unsigned)bf16rne(v0.x) | ((unsigned)bf16rne(v0.y) << 16);
    pk.y = (unsigned)bf16rne(v0.z) | ((unsigned)bf16rne(v0.w) << 16);
    pk.z = (unsigned)bf16rne(v1.x) | ((unsigned)bf16rne(v1.y) << 16);
    pk.w = (unsigned)bf16rne(v1.z) | ((unsigned)bf16rne(v1.w) << 16);
    *(uint4*)&xs[r * LDSP + c] = pk;
  }
  __syncthreads();

  // ---- layer 1: wave strip j0 = w*64 ----
  int j0 = w * 64;
  const unsigned short* W1Th = W1T + (size_t)h * 256 * 256;
  f32x4 acc[4][4];
#pragma unroll
  for (int mi = 0; mi < 4; ++mi)
#pragma unroll
    for (int ni = 0; ni < 4; ++ni) acc[mi][ni] = (f32x4){0.f, 0.f, 0.f, 0.f};

#pragma unroll
  for (int kk = 0; kk < 8; ++kk) {
    int k0 = kk * 32 + kb * 8;
    bf16x8 a[4], b[4];
#pragma unroll
    for (int mi = 0; mi < 4; ++mi)
      a[mi] = *(const bf16x8*)&xs[(mi * 16 + lr) * LDSP + k0];
#pragma unroll
    for (int ni = 0; ni < 4; ++ni)
      b[ni] = *(const bf16x8*)(W1Th + (size_t)(j0 + ni * 16 + lr) * 256 + k0);
#pragma unroll
    for (int mi = 0; mi < 4; ++mi)
#pragma unroll
      for (int ni = 0; ni < 4; ++ni)
        acc[mi][ni] = __builtin_amdgcn_mfma_f32_16x16x32_bf16(a[mi], b[ni],
                                                              acc[mi][ni], 0, 0, 0);
  }

  // ---- bias + relu -> hs (bf16) ----
  float b1v[4];
#pragma unroll
  for (int ni = 0; ni < 4; ++ni) b1v[ni] = b1[h * HID_DIM + j0 + ni * 16 + lr];
#pragma unroll
  for (int mi = 0; mi < 4; ++mi)
#pragma unroll
    for (int ni = 0; ni < 4; ++ni)
#pragma unroll
      for (int r = 0; r < 4; ++r) {
        float v = fmaxf(acc[mi][ni][r] + b1v[ni], 0.0f);
        hs[(mi * 16 + kb * 4 + r) * LDSP + (j0 + ni * 16 + lr)] = bf16rne(v);
      }
  __syncthreads();

  // ---- layer 2: wave row strip m in [w*16, w*16+16) ----
  const unsigned short* W2Th = W2T + (size_t)h * 64 * 256;
  f32x4 acc2[4];
#pragma unroll
  for (int ni = 0; ni < 4; ++ni) acc2[ni] = (f32x4){0.f, 0.f, 0.f, 0.f};
#pragma unroll
  for (int kk = 0; kk < 8; ++kk) {
    int k0 = kk * 32 + kb * 8;
    bf16x8 a = *(const bf16x8*)&hs[(w * 16 + lr) * LDSP + k0];
#pragma unroll
    for (int ni = 0; ni < 4; ++ni) {
      bf16x8 b = *(const bf16x8*)(W2Th + (size_t)(ni * 16 + lr) * 256 + k0);
      acc2[ni] = __builtin_amdgcn_mfma_f32_16x16x32_bf16(a, b, acc2[ni], 0, 0, 0);
    }
  }

  // ---- epilogue: feats (f32), s1/s2 via 16-lane reduce ----
  const float* awh = attn_w + h * ATT_STRIDE;
  float a1v[4], a2v[4], b2v[4];
#pragma unroll
  for (int ni = 0; ni < 4; ++ni) {
    int d = ni * 16 + lr;
    a1v[ni] = awh[d];
    a2v[ni] = awh[OUT_DIM + d];
    b2v[ni] = b2[h * OUT_DIM + d];
  }
#pragma unroll
  for (int r = 0; r < 4; ++r) {
    int n = n0 + w * 16 + kb * 4 + r;
    float vals[4];
    float p1 = 0.f, p2 = 0.f;
#pragma unroll
    for (int ni = 0; ni < 4; ++ni) {
      float v = acc2[ni][r] + b2v[ni];
      vals[ni] = v;
      p1 += v * a1v[ni];
      p2 += v * a2v[ni];
    }
#pragma unroll
    for (int m = 1; m < 16; m <<= 1) {
      p1 += __shfl_xor(p1, m, 64);
      p2 += __shfl_xor(p2, m, 64);
    }
    if (n < N) {
      float* fr = feats + ((size_t)h * N + n) * OUT_DIM;
#pragma unroll
      for (int ni = 0; ni < 4; ++ni) fr[ni * 16 + lr] = vals[ni];
      if (lr == 0) {
        s1[(size_t)h * N + n] = p1;
        s2[(size_t)h * N + n] = p2;
      }
    }
  }
}

// ---------------- global per-head max of edge scores ----------------

__global__ __launch_bounds__(256) void edgemax_kernel(
    const int* __restrict__ src, const int* __restrict__ dst,
    const float* __restrict__ elem, const float* __restrict__ s1,
    const float* __restrict__ s2, const float* __restrict__ attn_w,
    const float* __restrict__ attn_b, float* __restrict__ blockmax, int N, int E) {
  int e = blockIdx.x * 256 + threadIdx.x;
  float sc[N_HEADS];
  if (e < E) {
    int s = src[e], dn = dst[e];
    float el = elem[e];
#pragma unroll
    for (int h = 0; h < N_HEADS; ++h)
      sc[h] = s1[(size_t)h * N + s] + s2[(size_t)h * N + dn] +
              attn_w[h * ATT_STRIDE + 2 * OUT_DIM] * el + attn_b[h];
  } else {
#pragma unroll
    for (int h = 0; h < N_HEADS; ++h) sc[h] = -INFINITY;
  }
  __shared__ float wm[N_HEADS][4];
  int lane = threadIdx.x & 63, wv = threadIdx.x >> 6;
#pragma unroll
  for (int h = 0; h < N_HEADS; ++h) {
    float m = sc[h];
#pragma unroll
    for (int off = 32; off > 0; off >>= 1) m = fmaxf(m, __shfl_down(m, off, 64));
    if (lane == 0) wm[h][wv] = m;
  }
  __syncthreads();
  if (threadIdx.x < N_HEADS) {
    int h = threadIdx.x;
    float m = fmaxf(fmaxf(wm[h][0], wm[h][1]), fmaxf(wm[h][2], wm[h][3]));
    blockmax[blockIdx.x * N_HEADS + h] = m;
  }
}

__global__ __launch_bounds__(256) void reducemax_kernel(
    const float* __restrict__ blockmax, float* __restrict__ maxs, int nb) {
  __shared__ float red[256];
  int tid = threadIdx.x;
  for (int h = 0; h < N_HEADS; ++h) {
    float m = -INFINITY;
    for (int i = tid; i < nb; i += 256) m = fmaxf(m, blockmax[i * N_HEADS + h]);
    red[tid] = m;
    __syncthreads();
    for (int s = 128; s > 0; s >>= 1) {
      if (tid < s) red[tid] = fmaxf(red[tid], red[tid + s]);
      __syncthreads();
    }
    if (tid == 0) maxs[h] = red[0];
    __syncthreads();
  }
}

// ---------------- pull aggregation ----------------

__global__ __launch_bounds__(256) void aggregate_kernel(
    const int* __restrict__ dst, const float* __restrict__ elem,
    const int* __restrict__ offs, const int* __restrict__ eid,
    const float* __restrict__ s1, const float* __restrict__ s2,
    const float* __restrict__ feats, const float* __restrict__ attn_w,
    const float* __restrict__ attn_b, const float* __restrict__ maxs,
    float* __restrict__ out, int N) {
  int n = blockIdx.x;
  int h = threadIdx.x >> 6, d = threadIdx.x & 63;
  int beg = offs[n], end = offs[n + 1];
  float s1n = s1[(size_t)h * N + n];
  float awe = attn_w[h * ATT_STRIDE + 2 * OUT_DIM];
  float ab = attn_b[h];
  float mx = maxs[h];
  const float* fh = feats + (size_t)h * N * OUT_DIM;
  const float* s2h = s2 + (size_t)h * N;
  float acc = 0.f, rs = 0.f;
  for (int p = beg; p < end; ++p) {
    int e = eid[p];
    int dn = dst[e];
    float w = __expf(s1n + s2h[dn] + awe * elem[e] + ab - mx);
    acc = fmaf(w, fh[(size_t)dn * OUT_DIM + d], acc);
    rs += w;
  }
  out[(size_t)n * (N_HEADS * OUT_DIM) + h * OUT_DIM + d] = acc / rs;
}

// ---------------- launch ----------------

extern "C" void kernel_launch(void* const* d_in, const int* in_sizes, int n_in,
                              void* d_out, int out_size, void* d_ws, size_t ws_size,
                              hipStream_t stream) {
  const float* x = (const float*)d_in[0];
  const int* idx = (const int*)d_in[1];
  const float* elem = (const float*)d_in[2];
  const float* W1 = (const float*)d_in[3];
  const float* b1 = (const float*)d_in[4];
  const float* W2 = (const float*)d_in[5];
  const float* b2 = (const float*)d_in[6];
  const float* attn_w = (const float*)d_in[7];
  const float* attn_b = (const float*)d_in[8];
  float* out = (float*)d_out;

  int N = in_sizes[0] / IN_DIM; // 50000
  int E = in_sizes[2];          // 800000
  const int* src = idx;
  const int* dst = idx + E;
  int nb = (E + 255) / 256;

  // workspace layout (~58 MB)
  unsigned short* W1T = (unsigned short*)d_ws;             // 262144 bf16
  unsigned short* W2T = W1T + W1N;                         // 65536 bf16
  float* feats = (float*)(W2T + W2N);                      // H*N*64 f32
  float* s1 = feats + (size_t)N_HEADS * N * OUT_DIM;       // H*N
  float* s2 = s1 + (size_t)N_HEADS * N;                    // H*N
  float* blockmax = s2 + (size_t)N_HEADS * N;              // nb*H
  float* maxs = blockmax + (size_t)nb * N_HEADS;           // 4 (padded 64)
  int* offs = (int*)(maxs + 64);                           // N+1 (padded)
  int* cur = offs + (N + 64);                              // N
  int* eid = cur + (N + 64);                               // E

  convw_kernel<<<(W1N + W2N + 255) / 256, 256, 0, stream>>>(W1, W2, W1T, W2T);

  hipMemsetAsync(cur, 0, sizeof(int) * (size_t)N, stream);
  count_kernel<<<nb, 256, 0, stream>>>(src, cur, E);
  scan_kernel<<<1, 1024, 0, stream>>>(cur, offs, N);
  hipMemsetAsync(cur, 0, sizeof(int) * (size_t)N, stream);
  scatter_kernel<<<nb, 256, 0, stream>>>(src, offs, cur, eid, E);

  dim3 g((N + 63) / 64, N_HEADS);
  feats_kernel<<<g, 256, 0, stream>>>(x, W1T, b1, W2T, b2, attn_w, attn_b,
                                      feats, s1, s2, N);
  edgemax_kernel<<<nb, 256, 0, stream>>>(src, dst, elem, s1, s2, attn_w, attn_b,
                                         blockmax, N, E);
  reducemax_kernel<<<1, 256, 0, stream>>>(blockmax, maxs, nb);
  aggregate_kernel<<<N, 256, 0, stream>>>(dst, elem, offs, eid, s1, s2, feats,
                                          attn_w, attn_b, maxs, out, N);
}

// Round 8
// 565.139 us; speedup vs baseline: 2.6685x; 1.2592x over previous
//
#include <hip/hip_runtime.h>
#include <math.h>

// GNNLayer: 4-head GAT-like layer, MFMA edition.
//   feats[h] = relu(x @ W1[h] + b1[h]) @ W2[h] + b2[h]            [N,64]
//   score[e] = s1[src]+s2[dst]+aw_e*elem+ab ; w = exp(score - head_max)
//   out[n, h*64+d] = sum w*f_dst / sum w      (CSR-by-src pull, no atomics)
//
// R5: feats on v_mfma_f32_16x16x32_bf16 (1054 -> ~200us, total 711us).
// R7: aggregate was latency-bound (290us, VALUBusy 24%, 2.8 TB/s effective
//     gather vs 819 MB demand): serial chain eid->dst->feats per iteration.
//     Fix: scatter materializes CSR-ordered dst2/elem2 (no eid indirection),
//     aggregate unrolled x8 with batched loads -> 8-16 concurrent gathers.

#define N_HEADS 4
#define IN_DIM 256
#define HID_DIM 256
#define OUT_DIM 64
#define ATT_STRIDE (2 * OUT_DIM + 1) // 129
#define LDSP 264                     // padded bf16 row stride

typedef __attribute__((ext_vector_type(8))) short bf16x8;
typedef __attribute__((ext_vector_type(4))) float f32x4;

__device__ __forceinline__ unsigned short bf16rne(float f) {
  unsigned int u = __float_as_uint(f);
  u += 0x7fffu + ((u >> 16) & 1u);
  return (unsigned short)(u >> 16);
}

// ---------------- weight convert: W1T[h][j][k], W2T[h][d][k] in bf16 ----------------

#define W1N (N_HEADS * IN_DIM * HID_DIM)
#define W2N (N_HEADS * HID_DIM * OUT_DIM)

__global__ __launch_bounds__(256) void convw_kernel(const float* __restrict__ W1,
                                                    const float* __restrict__ W2,
                                                    unsigned short* __restrict__ W1T,
                                                    unsigned short* __restrict__ W2T) {
  int id = blockIdx.x * 256 + threadIdx.x;
  if (id < W1N) {
    int k = id & 255, j = (id >> 8) & 255, h = id >> 16;
    W1T[id] = bf16rne(W1[((size_t)h * 256 + k) * 256 + j]);
  } else if (id < W1N + W2N) {
    int t = id - W1N;
    int k = t & 255, d = (t >> 8) & 63, h = t >> 14;
    W2T[t] = bf16rne(W2[((size_t)h * 256 + k) * 64 + d]);
  }
}

// ---------------- CSR construction ----------------

__global__ __launch_bounds__(256) void count_kernel(const int* __restrict__ src,
                                                    int* __restrict__ cnt, int E) {
  int e = blockIdx.x * 256 + threadIdx.x;
  if (e < E) atomicAdd(&cnt[src[e]], 1);
}

__global__ __launch_bounds__(1024) void scan_kernel(const int* __restrict__ cnt,
                                                    int* __restrict__ offs, int N) {
  __shared__ int part[1024];
  int t = threadIdx.x;
  int chunk = (N + 1023) >> 10;
  int s0 = t * chunk;
  int s1e = min(s0 + chunk, N);
  int sum = 0;
  for (int i = s0; i < s1e; ++i) sum += cnt[i];
  part[t] = sum;
  __syncthreads();
  for (int off = 1; off < 1024; off <<= 1) {
    int v = (t >= off) ? part[t - off] : 0;
    __syncthreads();
    part[t] += v;
    __syncthreads();
  }
  int run = (t == 0) ? 0 : part[t - 1];
  for (int i = s0; i < s1e; ++i) { offs[i] = run; run += cnt[i]; }
  if (t == 0) offs[N] = part[1023];
}

// writes CSR-ordered dst/elem copies (no eid indirection in aggregate)
__global__ __launch_bounds__(256) void scatter_kernel(
    const int* __restrict__ src, const int* __restrict__ dst,
    const float* __restrict__ elem, const int* __restrict__ offs,
    int* __restrict__ cur, int* __restrict__ dst2, float* __restrict__ elem2,
    int E) {
  int e = blockIdx.x * 256 + threadIdx.x;
  if (e < E) {
    int s = src[e];
    int pos = offs[s] + atomicAdd(&cur[s], 1);
    dst2[pos] = dst[e];
    elem2[pos] = elem[e];
  }
}

// ---------------- fused MFMA MLP + attention projections ----------------
// grid: (ceil(N/64), N_HEADS), block 256 = 4 waves.
// Fragment maps (verified m89/m92): A/B lane&15=m/n, k=8*(lane>>4)+j;
//                                   D col=lane&15, row=4*(lane>>4)+reg.

__global__ __launch_bounds__(256) void feats_kernel(
    const float* __restrict__ x, const unsigned short* __restrict__ W1T,
    const float* __restrict__ b1, const unsigned short* __restrict__ W2T,
    const float* __restrict__ b2, const float* __restrict__ attn_w,
    const float* __restrict__ attn_b, float* __restrict__ feats,
    float* __restrict__ s1, float* __restrict__ s2, int N) {
  __shared__ __align__(16) unsigned short xs[64 * LDSP]; // 33.8 KB
  __shared__ __align__(16) unsigned short hs[64 * LDSP]; // 33.8 KB

  int h = blockIdx.y;
  int n0 = blockIdx.x * 64;
  int tid = threadIdx.x;
  int w = tid >> 6, l = tid & 63;
  int lr = l & 15, kb = l >> 4;

  // ---- stage x tile (f32 -> bf16 LDS), zero-fill rows >= N ----
#pragma unroll
  for (int i = 0; i < 8; ++i) {
    int flat = i * 2048 + tid * 8;
    int r = flat >> 8, c = flat & 255;
    int n = n0 + r;
    float4 v0 = make_float4(0.f, 0.f, 0.f, 0.f), v1 = v0;
    if (n < N) {
      const float* p = x + (size_t)n * IN_DIM + c;
      v0 = *(const float4*)p;
      v1 = *(const float4*)(p + 4);
    }
    uint4 pk;
    pk.x = (unsigned)bf16rne(v0.x) | ((unsigned)bf16rne(v0.y) << 16);
    pk.y = (unsigned)bf16rne(v0.z) | ((unsigned)bf16rne(v0.w) << 16);
    pk.z = (unsigned)bf16rne(v1.x) | ((unsigned)bf16rne(v1.y) << 16);
    pk.w = (unsigned)bf16rne(v1.z) | ((unsigned)bf16rne(v1.w) << 16);
    *(uint4*)&xs[r * LDSP + c] = pk;
  }
  __syncthreads();

  // ---- layer 1: wave strip j0 = w*64 ----
  int j0 = w * 64;
  const unsigned short* W1Th = W1T + (size_t)h * 256 * 256;
  f32x4 acc[4][4];
#pragma unroll
  for (int mi = 0; mi < 4; ++mi)
#pragma unroll
    for (int ni = 0; ni < 4; ++ni) acc[mi][ni] = (f32x4){0.f, 0.f, 0.f, 0.f};

#pragma unroll
  for (int kk = 0; kk < 8; ++kk) {
    int k0 = kk * 32 + kb * 8;
    bf16x8 a[4], b[4];
#pragma unroll
    for (int mi = 0; mi < 4; ++mi)
      a[mi] = *(const bf16x8*)&xs[(mi * 16 + lr) * LDSP + k0];
#pragma unroll
    for (int ni = 0; ni < 4; ++ni)
      b[ni] = *(const bf16x8*)(W1Th + (size_t)(j0 + ni * 16 + lr) * 256 + k0);
#pragma unroll
    for (int mi = 0; mi < 4; ++mi)
#pragma unroll
      for (int ni = 0; ni < 4; ++ni)
        acc[mi][ni] = __builtin_amdgcn_mfma_f32_16x16x32_bf16(a[mi], b[ni],
                                                              acc[mi][ni], 0, 0, 0);
  }

  // ---- bias + relu -> hs (bf16) ----
  float b1v[4];
#pragma unroll
  for (int ni = 0; ni < 4; ++ni) b1v[ni] = b1[h * HID_DIM + j0 + ni * 16 + lr];
#pragma unroll
  for (int mi = 0; mi < 4; ++mi)
#pragma unroll
    for (int ni = 0; ni < 4; ++ni)
#pragma unroll
      for (int r = 0; r < 4; ++r) {
        float v = fmaxf(acc[mi][ni][r] + b1v[ni], 0.0f);
        hs[(mi * 16 + kb * 4 + r) * LDSP + (j0 + ni * 16 + lr)] = bf16rne(v);
      }
  __syncthreads();

  // ---- layer 2: wave row strip m in [w*16, w*16+16) ----
  const unsigned short* W2Th = W2T + (size_t)h * 64 * 256;
  f32x4 acc2[4];
#pragma unroll
  for (int ni = 0; ni < 4; ++ni) acc2[ni] = (f32x4){0.f, 0.f, 0.f, 0.f};
#pragma unroll
  for (int kk = 0; kk < 8; ++kk) {
    int k0 = kk * 32 + kb * 8;
    bf16x8 a = *(const bf16x8*)&hs[(w * 16 + lr) * LDSP + k0];
#pragma unroll
    for (int ni = 0; ni < 4; ++ni) {
      bf16x8 b = *(const bf16x8*)(W2Th + (size_t)(ni * 16 + lr) * 256 + k0);
      acc2[ni] = __builtin_amdgcn_mfma_f32_16x16x32_bf16(a, b, acc2[ni], 0, 0, 0);
    }
  }

  // ---- epilogue: feats (f32), s1/s2 via 16-lane reduce ----
  const float* awh = attn_w + h * ATT_STRIDE;
  float a1v[4], a2v[4], b2v[4];
#pragma unroll
  for (int ni = 0; ni < 4; ++ni) {
    int d = ni * 16 + lr;
    a1v[ni] = awh[d];
    a2v[ni] = awh[OUT_DIM + d];
    b2v[ni] = b2[h * OUT_DIM + d];
  }
#pragma unroll
  for (int r = 0; r < 4; ++r) {
    int n = n0 + w * 16 + kb * 4 + r;
    float vals[4];
    float p1 = 0.f, p2 = 0.f;
#pragma unroll
    for (int ni = 0; ni < 4; ++ni) {
      float v = acc2[ni][r] + b2v[ni];
      vals[ni] = v;
      p1 += v * a1v[ni];
      p2 += v * a2v[ni];
    }
#pragma unroll
    for (int m = 1; m < 16; m <<= 1) {
      p1 += __shfl_xor(p1, m, 64);
      p2 += __shfl_xor(p2, m, 64);
    }
    if (n < N) {
      float* fr = feats + ((size_t)h * N + n) * OUT_DIM;
#pragma unroll
      for (int ni = 0; ni < 4; ++ni) fr[ni * 16 + lr] = vals[ni];
      if (lr == 0) {
        s1[(size_t)h * N + n] = p1;
        s2[(size_t)h * N + n] = p2;
      }
    }
  }
}

// ---------------- global per-head max of edge scores ----------------

__global__ __launch_bounds__(256) void edgemax_kernel(
    const int* __restrict__ src, const int* __restrict__ dst,
    const float* __restrict__ elem, const float* __restrict__ s1,
    const float* __restrict__ s2, const float* __restrict__ attn_w,
    const float* __restrict__ attn_b, float* __restrict__ blockmax, int N, int E) {
  int e = blockIdx.x * 256 + threadIdx.x;
  float sc[N_HEADS];
  if (e < E) {
    int s = src[e], dn = dst[e];
    float el = elem[e];
#pragma unroll
    for (int h = 0; h < N_HEADS; ++h)
      sc[h] = s1[(size_t)h * N + s] + s2[(size_t)h * N + dn] +
              attn_w[h * ATT_STRIDE + 2 * OUT_DIM] * el + attn_b[h];
  } else {
#pragma unroll
    for (int h = 0; h < N_HEADS; ++h) sc[h] = -INFINITY;
  }
  __shared__ float wm[N_HEADS][4];
  int lane = threadIdx.x & 63, wv = threadIdx.x >> 6;
#pragma unroll
  for (int h = 0; h < N_HEADS; ++h) {
    float m = sc[h];
#pragma unroll
    for (int off = 32; off > 0; off >>= 1) m = fmaxf(m, __shfl_down(m, off, 64));
    if (lane == 0) wm[h][wv] = m;
  }
  __syncthreads();
  if (threadIdx.x < N_HEADS) {
    int h = threadIdx.x;
    float m = fmaxf(fmaxf(wm[h][0], wm[h][1]), fmaxf(wm[h][2], wm[h][3]));
    blockmax[blockIdx.x * N_HEADS + h] = m;
  }
}

__global__ __launch_bounds__(256) void reducemax_kernel(
    const float* __restrict__ blockmax, float* __restrict__ maxs, int nb) {
  __shared__ float red[256];
  int tid = threadIdx.x;
  for (int h = 0; h < N_HEADS; ++h) {
    float m = -INFINITY;
    for (int i = tid; i < nb; i += 256) m = fmaxf(m, blockmax[i * N_HEADS + h]);
    red[tid] = m;
    __syncthreads();
    for (int s = 128; s > 0; s >>= 1) {
      if (tid < s) red[tid] = fmaxf(red[tid], red[tid + s]);
      __syncthreads();
    }
    if (tid == 0) maxs[h] = red[0];
    __syncthreads();
  }
}

// ---------------- pull aggregation (unroll-8, batched loads for MLP) ----------------
// block = 4 waves = 4 heads for node blockIdx.x; lane = output dim.

#define AGG_U 8

__global__ __launch_bounds__(256) void aggregate_kernel(
    const int* __restrict__ dst2, const float* __restrict__ elem2,
    const int* __restrict__ offs, const float* __restrict__ s1,
    const float* __restrict__ s2, const float* __restrict__ feats,
    const float* __restrict__ attn_w, const float* __restrict__ attn_b,
    const float* __restrict__ maxs, float* __restrict__ out, int N) {
  int n = blockIdx.x;
  int h = threadIdx.x >> 6, d = threadIdx.x & 63;
  int beg = offs[n], end = offs[n + 1];
  float s1n = s1[(size_t)h * N + n];
  float awe = attn_w[h * ATT_STRIDE + 2 * OUT_DIM];
  float ab = attn_b[h];
  float mx = maxs[h];
  const float* fh = feats + (size_t)h * N * OUT_DIM;
  const float* s2h = s2 + (size_t)h * N;
  float acc = 0.f, rs = 0.f;
  float base = s1n + ab - mx;

  for (int p = beg; p < end; p += AGG_U) {
    int dn[AGG_U];
    float el[AGG_U];
#pragma unroll
    for (int i = 0; i < AGG_U; ++i) {
      int q = (p + i < end) ? p + i : beg; // beg is valid whenever loop runs
      dn[i] = dst2[q];
      el[i] = elem2[q];
    }
    float s2v[AGG_U], fv[AGG_U];
#pragma unroll
    for (int i = 0; i < AGG_U; ++i) s2v[i] = s2h[dn[i]];
#pragma unroll
    for (int i = 0; i < AGG_U; ++i) fv[i] = fh[(size_t)dn[i] * OUT_DIM + d];
#pragma unroll
    for (int i = 0; i < AGG_U; ++i) {
      float wv = (p + i < end) ? __expf(base + s2v[i] + awe * el[i]) : 0.f;
      acc = fmaf(wv, fv[i], acc);
      rs += wv;
    }
  }
  out[(size_t)n * (N_HEADS * OUT_DIM) + h * OUT_DIM + d] = acc / rs;
}

// ---------------- launch ----------------

extern "C" void kernel_launch(void* const* d_in, const int* in_sizes, int n_in,
                              void* d_out, int out_size, void* d_ws, size_t ws_size,
                              hipStream_t stream) {
  const float* x = (const float*)d_in[0];
  const int* idx = (const int*)d_in[1];
  const float* elem = (const float*)d_in[2];
  const float* W1 = (const float*)d_in[3];
  const float* b1 = (const float*)d_in[4];
  const float* W2 = (const float*)d_in[5];
  const float* b2 = (const float*)d_in[6];
  const float* attn_w = (const float*)d_in[7];
  const float* attn_b = (const float*)d_in[8];
  float* out = (float*)d_out;

  int N = in_sizes[0] / IN_DIM; // 50000
  int E = in_sizes[2];          // 800000
  const int* src = idx;
  const int* dst = idx + E;
  int nb = (E + 255) / 256;

  // workspace layout (~61 MB)
  unsigned short* W1T = (unsigned short*)d_ws;             // 262144 bf16
  unsigned short* W2T = W1T + W1N;                         // 65536 bf16
  float* feats = (float*)(W2T + W2N);                      // H*N*64 f32
  float* s1 = feats + (size_t)N_HEADS * N * OUT_DIM;       // H*N
  float* s2 = s1 + (size_t)N_HEADS * N;                    // H*N
  float* blockmax = s2 + (size_t)N_HEADS * N;              // nb*H
  float* maxs = blockmax + (size_t)nb * N_HEADS;           // 4 (padded 64)
  int* offs = (int*)(maxs + 64);                           // N+1 (padded)
  int* cur = offs + (N + 64);                              // N
  int* dst2 = cur + (N + 64);                              // E
  float* elem2 = (float*)(dst2 + E);                       // E

  convw_kernel<<<(W1N + W2N + 255) / 256, 256, 0, stream>>>(W1, W2, W1T, W2T);

  hipMemsetAsync(cur, 0, sizeof(int) * (size_t)N, stream);
  count_kernel<<<nb, 256, 0, stream>>>(src, cur, E);
  scan_kernel<<<1, 1024, 0, stream>>>(cur, offs, N);
  hipMemsetAsync(cur, 0, sizeof(int) * (size_t)N, stream);
  scatter_kernel<<<nb, 256, 0, stream>>>(src, dst, elem, offs, cur, dst2, elem2, E);

  dim3 g((N + 63) / 64, N_HEADS);
  feats_kernel<<<g, 256, 0, stream>>>(x, W1T, b1, W2T, b2, attn_w, attn_b,
                                      feats, s1, s2, N);
  edgemax_kernel<<<nb, 256, 0, stream>>>(src, dst, elem, s1, s2, attn_w, attn_b,
                                         blockmax, N, E);
  reducemax_kernel<<<1, 256, 0, stream>>>(blockmax, maxs, nb);
  aggregate_kernel<<<N, 256, 0, stream>>>(dst2, elem2, offs, s1, s2, feats,
                                          attn_w, attn_b, maxs, out, N);
}

// Round 11
// 499.888 us; speedup vs baseline: 3.0168x; 1.1305x over previous
//
#include <hip/hip_runtime.h>
#include <math.h>

// GNNLayer: 4-head GAT-like layer, MFMA edition.
//   feats[h] = relu(x @ W1[h] + b1[h]) @ W2[h] + b2[h]            [N,64]
//   score[e] = s1[src]+s2[dst]+aw_e*elem+ab ; w = exp(score)  (shift-invariant:
//   out = sum w*f / sum w, so the reference's global-max subtraction cancels)
//   out[n, h*64+d] = sum_{e: src=n} w*f_dst[d] / sum w   (CSR pull, no atomics)
//
// R5: feats on MFMA (1054->~200us). R7: aggregate unroll-8 (290->133us).
// R8: (1) feats merges 4 heads per block: x staged ONCE, bf16 feats_g out,
//     packed s1p/s2p[n][4]. (2) aggregate gathers bf16 rows, 2 edges in
//     flight per wave (lane-half split), dword loads. (3) edgemax/reducemax
//     deleted (shift invariance of the weighted average).

#define N_HEADS 4
#define IN_DIM 256
#define HID_DIM 256
#define OUT_DIM 64
#define ATT_STRIDE (2 * OUT_DIM + 1) // 129
#define LDSP 264                     // padded bf16 row stride

typedef __attribute__((ext_vector_type(8))) short bf16x8;
typedef __attribute__((ext_vector_type(4))) float f32x4;

__device__ __forceinline__ unsigned short bf16rne(float f) {
  unsigned int u = __float_as_uint(f);
  u += 0x7fffu + ((u >> 16) & 1u);
  return (unsigned short)(u >> 16);
}

// ---------------- weight convert: W1T[h][j][k], W2T[h][d][k] in bf16 ----------------

#define W1N (N_HEADS * IN_DIM * HID_DIM)
#define W2N (N_HEADS * HID_DIM * OUT_DIM)

__global__ __launch_bounds__(256) void convw_kernel(const float* __restrict__ W1,
                                                    const float* __restrict__ W2,
                                                    unsigned short* __restrict__ W1T,
                                                    unsigned short* __restrict__ W2T) {
  int id = blockIdx.x * 256 + threadIdx.x;
  if (id < W1N) {
    int k = id & 255, j = (id >> 8) & 255, h = id >> 16;
    W1T[id] = bf16rne(W1[((size_t)h * 256 + k) * 256 + j]);
  } else if (id < W1N + W2N) {
    int t = id - W1N;
    int k = t & 255, d = (t >> 8) & 63, h = t >> 14;
    W2T[t] = bf16rne(W2[((size_t)h * 256 + k) * 64 + d]);
  }
}

// ---------------- CSR construction ----------------

__global__ __launch_bounds__(256) void count_kernel(const int* __restrict__ src,
                                                    int* __restrict__ cnt, int E) {
  int e = blockIdx.x * 256 + threadIdx.x;
  if (e < E) atomicAdd(&cnt[src[e]], 1);
}

__global__ __launch_bounds__(1024) void scan_kernel(const int* __restrict__ cnt,
                                                    int* __restrict__ offs, int N) {
  __shared__ int part[1024];
  int t = threadIdx.x;
  int chunk = (N + 1023) >> 10;
  int s0 = t * chunk;
  int s1e = min(s0 + chunk, N);
  int sum = 0;
  for (int i = s0; i < s1e; ++i) sum += cnt[i];
  part[t] = sum;
  __syncthreads();
  for (int off = 1; off < 1024; off <<= 1) {
    int v = (t >= off) ? part[t - off] : 0;
    __syncthreads();
    part[t] += v;
    __syncthreads();
  }
  int run = (t == 0) ? 0 : part[t - 1];
  for (int i = s0; i < s1e; ++i) { offs[i] = run; run += cnt[i]; }
  if (t == 0) offs[N] = part[1023];
}

// writes CSR-ordered dst/elem copies (no eid indirection in aggregate)
__global__ __launch_bounds__(256) void scatter_kernel(
    const int* __restrict__ src, const int* __restrict__ dst,
    const float* __restrict__ elem, const int* __restrict__ offs,
    int* __restrict__ cur, int* __restrict__ dst2, float* __restrict__ elem2,
    int E) {
  int e = blockIdx.x * 256 + threadIdx.x;
  if (e < E) {
    int s = src[e];
    int pos = offs[s] + atomicAdd(&cur[s], 1);
    dst2[pos] = dst[e];
    elem2[pos] = elem[e];
  }
}

// ---------------- fused MFMA MLP, all 4 heads per block ----------------
// grid: ceil(N/64), block 256 = 4 waves. Stage x tile once; loop heads.
// Fragment maps (verified m89/m92): A/B lane&15=m/n, k=8*(lane>>4)+j;
//                                   D col=lane&15, row=4*(lane>>4)+reg.

__global__ __launch_bounds__(256) void feats_kernel(
    const float* __restrict__ x, const unsigned short* __restrict__ W1T,
    const float* __restrict__ b1, const unsigned short* __restrict__ W2T,
    const float* __restrict__ b2, const float* __restrict__ attn_w,
    const float* __restrict__ attn_b, unsigned short* __restrict__ feats_g,
    float* __restrict__ s1p, float* __restrict__ s2p, int N) {
  __shared__ __align__(16) unsigned short xs[64 * LDSP]; // 33.8 KB
  __shared__ __align__(16) unsigned short hs[64 * LDSP]; // 33.8 KB

  int n0 = blockIdx.x * 64;
  int tid = threadIdx.x;
  int w = tid >> 6, l = tid & 63;
  int lr = l & 15, kb = l >> 4;

  // ---- stage x tile ONCE (f32 -> bf16 LDS), zero-fill rows >= N ----
#pragma unroll
  for (int i = 0; i < 8; ++i) {
    int flat = i * 2048 + tid * 8;
    int r = flat >> 8, c = flat & 255;
    int n = n0 + r;
    float4 v0 = make_float4(0.f, 0.f, 0.f, 0.f), v1 = v0;
    if (n < N) {
      const float* p = x + (size_t)n * IN_DIM + c;
      v0 = *(const float4*)p;
      v1 = *(const float4*)(p + 4);
    }
    uint4 pk;
    pk.x = (unsigned)bf16rne(v0.x) | ((unsigned)bf16rne(v0.y) << 16);
    pk.y = (unsigned)bf16rne(v0.z) | ((unsigned)bf16rne(v0.w) << 16);
    pk.z = (unsigned)bf16rne(v1.x) | ((unsigned)bf16rne(v1.y) << 16);
    pk.w = (unsigned)bf16rne(v1.z) | ((unsigned)bf16rne(v1.w) << 16);
    *(uint4*)&xs[r * LDSP + c] = pk;
  }
  __syncthreads();

  int j0 = w * 64;
  for (int h = 0; h < N_HEADS; ++h) {
    // ---- layer 1: wave strip j0 ----
    const unsigned short* W1Th = W1T + (size_t)h * 256 * 256;
    f32x4 acc[4][4];
#pragma unroll
    for (int mi = 0; mi < 4; ++mi)
#pragma unroll
      for (int ni = 0; ni < 4; ++ni) acc[mi][ni] = (f32x4){0.f, 0.f, 0.f, 0.f};

#pragma unroll
    for (int kk = 0; kk < 8; ++kk) {
      int k0 = kk * 32 + kb * 8;
      bf16x8 a[4], b[4];
#pragma unroll
      for (int mi = 0; mi < 4; ++mi)
        a[mi] = *(const bf16x8*)&xs[(mi * 16 + lr) * LDSP + k0];
#pragma unroll
      for (int ni = 0; ni < 4; ++ni)
        b[ni] = *(const bf16x8*)(W1Th + (size_t)(j0 + ni * 16 + lr) * 256 + k0);
#pragma unroll
      for (int mi = 0; mi < 4; ++mi)
#pragma unroll
        for (int ni = 0; ni < 4; ++ni)
          acc[mi][ni] = __builtin_amdgcn_mfma_f32_16x16x32_bf16(a[mi], b[ni],
                                                                acc[mi][ni], 0, 0, 0);
    }

    // ---- bias + relu -> hs (sync a: prev head's layer-2 reads done) ----
    float b1v[4];
#pragma unroll
    for (int ni = 0; ni < 4; ++ni) b1v[ni] = b1[h * HID_DIM + j0 + ni * 16 + lr];
    __syncthreads();
#pragma unroll
    for (int mi = 0; mi < 4; ++mi)
#pragma unroll
      for (int ni = 0; ni < 4; ++ni)
#pragma unroll
        for (int r = 0; r < 4; ++r) {
          float v = fmaxf(acc[mi][ni][r] + b1v[ni], 0.0f);
          hs[(mi * 16 + kb * 4 + r) * LDSP + (j0 + ni * 16 + lr)] = bf16rne(v);
        }
    __syncthreads();

    // ---- layer 2: wave row strip [w*16, w*16+16) ----
    const unsigned short* W2Th = W2T + (size_t)h * 64 * 256;
    f32x4 acc2[4];
#pragma unroll
    for (int ni = 0; ni < 4; ++ni) acc2[ni] = (f32x4){0.f, 0.f, 0.f, 0.f};
#pragma unroll
    for (int kk = 0; kk < 8; ++kk) {
      int k0 = kk * 32 + kb * 8;
      bf16x8 a = *(const bf16x8*)&hs[(w * 16 + lr) * LDSP + k0];
#pragma unroll
      for (int ni = 0; ni < 4; ++ni) {
        bf16x8 b = *(const bf16x8*)(W2Th + (size_t)(ni * 16 + lr) * 256 + k0);
        acc2[ni] = __builtin_amdgcn_mfma_f32_16x16x32_bf16(a, b, acc2[ni], 0, 0, 0);
      }
    }

    // ---- epilogue: feats_g (bf16), s1p/s2p via 16-lane reduce ----
    const float* awh = attn_w + h * ATT_STRIDE;
    float a1v[4], a2v[4], b2v[4];
#pragma unroll
    for (int ni = 0; ni < 4; ++ni) {
      int d = ni * 16 + lr;
      a1v[ni] = awh[d];
      a2v[ni] = awh[OUT_DIM + d];
      b2v[ni] = b2[h * OUT_DIM + d];
    }
#pragma unroll
    for (int r = 0; r < 4; ++r) {
      int n = n0 + w * 16 + kb * 4 + r;
      float vals[4];
      float p1 = 0.f, p2 = 0.f;
#pragma unroll
      for (int ni = 0; ni < 4; ++ni) {
        float v = acc2[ni][r] + b2v[ni];
        vals[ni] = v;
        p1 += v * a1v[ni];
        p2 += v * a2v[ni];
      }
#pragma unroll
      for (int m = 1; m < 16; m <<= 1) {
        p1 += __shfl_xor(p1, m, 64);
        p2 += __shfl_xor(p2, m, 64);
      }
      if (n < N) {
        unsigned short* fr = feats_g + ((size_t)h * N + n) * OUT_DIM;
#pragma unroll
        for (int ni = 0; ni < 4; ++ni) fr[ni * 16 + lr] = bf16rne(vals[ni]);
        if (lr == 0) {
          s1p[(size_t)n * N_HEADS + h] = p1;
          s2p[(size_t)n * N_HEADS + h] = p2;
        }
      }
    }
  }
}

// ---------------- pull aggregation ----------------
// block = 4 waves (one per head) for node blockIdx.x.
// wave: lane half j=l>>5 processes edges of parity j; lane pair-dim dp=l&31
// covers dims {2dp, 2dp+1} via one dword (2 bf16) load per feats row.

#define AGG_U 8

__global__ __launch_bounds__(256) void aggregate_kernel(
    const int* __restrict__ dst2, const float* __restrict__ elem2,
    const int* __restrict__ offs, const float* __restrict__ s1p,
    const float* __restrict__ s2p, const unsigned short* __restrict__ feats_g,
    const float* __restrict__ attn_w, const float* __restrict__ attn_b,
    float* __restrict__ out, int N) {
  int n = blockIdx.x;
  int h = threadIdx.x >> 6;
  int l = threadIdx.x & 63;
  int j = l >> 5, dp = l & 31;
  int beg = offs[n], end = offs[n + 1];
  float base = s1p[(size_t)n * N_HEADS + h] + attn_b[h];
  float awe = attn_w[h * ATT_STRIDE + 2 * OUT_DIM];
  const unsigned short* fg = feats_g + (size_t)h * N * OUT_DIM;
  float acc0 = 0.f, acc1 = 0.f, rs = 0.f;

  for (int p = beg; p < end; p += 2 * AGG_U) {
    int dn[AGG_U];
    float el[AGG_U];
#pragma unroll
    for (int i = 0; i < AGG_U; ++i) {
      int q = p + 2 * i + j;
      int qq = (q < end) ? q : beg; // beg valid whenever loop body runs
      dn[i] = dst2[qq];
      el[i] = elem2[qq];
    }
    float s2v[AGG_U];
    unsigned int fv[AGG_U];
#pragma unroll
    for (int i = 0; i < AGG_U; ++i) s2v[i] = s2p[(size_t)dn[i] * N_HEADS + h];
#pragma unroll
    for (int i = 0; i < AGG_U; ++i)
      fv[i] = *(const unsigned int*)&fg[(size_t)dn[i] * OUT_DIM + 2 * dp];
#pragma unroll
    for (int i = 0; i < AGG_U; ++i) {
      float wv = (p + 2 * i + j < end) ? __expf(base + s2v[i] + awe * el[i]) : 0.f;
      float f0 = __uint_as_float(fv[i] << 16);
      float f1 = __uint_as_float(fv[i] & 0xffff0000u);
      acc0 = fmaf(wv, f0, acc0);
      acc1 = fmaf(wv, f1, acc1);
      rs += wv;
    }
  }
  // combine the two edge-parity halves (lane l <-> l^32)
  acc0 += __shfl_xor(acc0, 32, 64);
  acc1 += __shfl_xor(acc1, 32, 64);
  rs += __shfl_xor(rs, 32, 64);
  if (j == 0) {
    float inv = 1.0f / rs;
    float2 o = make_float2(acc0 * inv, acc1 * inv);
    *(float2*)&out[(size_t)n * (N_HEADS * OUT_DIM) + h * OUT_DIM + 2 * dp] = o;
  }
}

// ---------------- launch ----------------

extern "C" void kernel_launch(void* const* d_in, const int* in_sizes, int n_in,
                              void* d_out, int out_size, void* d_ws, size_t ws_size,
                              hipStream_t stream) {
  const float* x = (const float*)d_in[0];
  const int* idx = (const int*)d_in[1];
  const float* elem = (const float*)d_in[2];
  const float* W1 = (const float*)d_in[3];
  const float* b1 = (const float*)d_in[4];
  const float* W2 = (const float*)d_in[5];
  const float* b2 = (const float*)d_in[6];
  const float* attn_w = (const float*)d_in[7];
  const float* attn_b = (const float*)d_in[8];
  float* out = (float*)d_out;

  int N = in_sizes[0] / IN_DIM; // 50000
  int E = in_sizes[2];          // 800000
  const int* src = idx;
  const int* dst = idx + E;
  int nb = (E + 255) / 256;

  // workspace layout (~35 MB)
  unsigned short* W1T = (unsigned short*)d_ws;                  // 262144 bf16
  unsigned short* W2T = W1T + W1N;                              // 65536 bf16
  unsigned short* feats_g = W2T + W2N;                          // H*N*64 bf16
  float* s1p = (float*)(feats_g + (size_t)N_HEADS * N * OUT_DIM); // N*4
  float* s2p = s1p + (size_t)N * N_HEADS;                       // N*4
  int* offs = (int*)(s2p + (size_t)N * N_HEADS);                // N+1 (padded)
  int* cur = offs + (N + 64);                                   // N (padded)
  int* dst2 = cur + (N + 64);                                   // E
  float* elem2 = (float*)(dst2 + E);                            // E

  convw_kernel<<<(W1N + W2N + 255) / 256, 256, 0, stream>>>(W1, W2, W1T, W2T);

  hipMemsetAsync(cur, 0, sizeof(int) * (size_t)N, stream);
  count_kernel<<<nb, 256, 0, stream>>>(src, cur, E);
  scan_kernel<<<1, 1024, 0, stream>>>(cur, offs, N);
  hipMemsetAsync(cur, 0, sizeof(int) * (size_t)N, stream);
  scatter_kernel<<<nb, 256, 0, stream>>>(src, dst, elem, offs, cur, dst2, elem2, E);

  feats_kernel<<<(N + 63) / 64, 256, 0, stream>>>(x, W1T, b1, W2T, b2, attn_w,
                                                  attn_b, feats_g, s1p, s2p, N);
  aggregate_kernel<<<N, 256, 0, stream>>>(dst2, elem2, offs, s1p, s2p, feats_g,
                                          attn_w, attn_b, out, N);
}